// Round 1
// baseline (891.971 us; speedup 1.0000x reference)
//
#include <hip/hip_runtime.h>
#include <math.h>

#define NN    1000000
#define DEG   64
#define BATCH 4096
#define NS    25
#define EMB   64
#define HD    128

// workspace layout (float offsets)
#define OFF_A1T    0            // 64x128   A1^T  (d-major, k inner)
#define OFF_A1NT   8192         // 64x128   A1n^T
#define OFF_W2XBT  16384        // 128x128  w2x[:,128:]^T
#define OFF_W2NLO  32768        // 128x128  w2n[:,:128]^T
#define OFF_W2NHI  49152        // 128x128  w2n[:,128:]^T
#define OFF_C1X    65536        // 128
#define OFF_C1N    65664        // 128
#define OFF_V0     65792        // 128
#define OFF_IDS1   66560        // int32 region, 102400 ids
#define OFF_ME1    168960       // 4096x64   meanE1
#define OFF_X1     431104       // 102400x64 E[ids1]
#define OFF_ME2    6984704      // 102400x64 meanE2
#define OFF_MH1    13538304     // 4096x256  meanH1
#define OFF_G0     14586880     // 4096x128  g0
// total 15111168 floats = ~60.4 MB

// ---------------------------------------------------------------- K0: tiny precompute
__global__ void k0_prep(const float* __restrict__ emb, const float* __restrict__ prepW,
                        const float* __restrict__ prepb,
                        const float* __restrict__ w1x, const float* __restrict__ w1n,
                        const float* __restrict__ w2x, const float* __restrict__ w2n,
                        float* __restrict__ ws) {
  int t = threadIdx.x;
  int b = blockIdx.x;
  if (b == 0 || b == 1) {
    // A = W @ prep_W  (stored transposed, d-major), c = W @ prep_b
    const float* W = (b == 0) ? w1x : w1n;
    float* At = ws + ((b == 0) ? OFF_A1T : OFF_A1NT);
    float* c  = ws + ((b == 0) ? OFF_C1X : OFF_C1N);
    for (int idx = t; idx < 128 * 64; idx += 256) {
      int k = idx & 127, d = idx >> 7;
      float s = 0.f;
      for (int a = 0; a < 64; ++a) s += W[k * 64 + a] * prepW[a * 64 + d];
      At[d * 128 + k] = s;
    }
    if (t < 128) {
      float s = 0.f;
      for (int a = 0; a < 64; ++a) s += W[t * 64 + a] * prepb[a];
      c[t] = s;
    }
  } else if (b == 2) {
    // transposes of the layer-2 weights
    for (int idx = t; idx < 128 * 128; idx += 256) {
      int k = idx & 127, d = idx >> 7;
      ws[OFF_W2XBT + d * 128 + k] = w2x[k * 256 + 128 + d];
      ws[OFF_W2NLO + d * 128 + k] = w2n[k * 256 + d];
      ws[OFF_W2NHI + d * 128 + k] = w2n[k * 256 + 128 + d];
    }
  } else {
    // e0 = E[NN] @ prepW^T + prepb ; u = relu(e0 @ w1x^T) ; v0 = u @ w2x[:,:128]^T
    __shared__ float e0[64], u[128];
    if (t < 64) {
      float s = prepb[t];
      for (int d = 0; d < 64; ++d) s += emb[(size_t)NN * 64 + d] * prepW[t * 64 + d];
      e0[t] = s;
    }
    __syncthreads();
    if (t < 128) {
      float s = 0.f;
      for (int a = 0; a < 64; ++a) s += w1x[t * 64 + a] * e0[a];
      u[t] = fmaxf(s, 0.f);
    }
    __syncthreads();
    if (t < 128) {
      float s = 0.f;
      for (int k = 0; k < 128; ++k) s += u[k] * w2x[t * 256 + k];
      ws[OFF_V0 + t] = s;
    }
  }
}

// ---------------------------------------------------------------- K1: hop-1 sample + meanE1
__global__ void k1_hop1(const int* __restrict__ ids, const int* __restrict__ adj,
                        const int* __restrict__ perm1, const float* __restrict__ emb,
                        float* __restrict__ ws) {
  int lane = threadIdx.x & 63;
  int i = blockIdx.x * 4 + (threadIdx.x >> 6);   // one wave per batch row
  int node = ids[i];
  int nb = 0;
  if (lane < NS) nb = adj[node * DEG + perm1[lane]];
  float acc = 0.f;
#pragma unroll
  for (int j = 0; j < NS; ++j) {
    int nid = __shfl(nb, j, 64);
    acc += emb[(size_t)nid * EMB + lane];
  }
  ws[OFF_ME1 + i * EMB + lane] = acc * (1.f / NS);
  int* ids1 = (int*)(ws + OFF_IDS1);
  if (lane < NS) ids1[i * NS + lane] = nb;
}

// ---------------------------------------------------------------- K2a: hop-2 gather (the hot one)
__global__ void k2a_hop2(const int* __restrict__ adj, const int* __restrict__ perm2,
                         const float* __restrict__ emb, float* __restrict__ ws) {
  int lane = threadIdx.x & 63;
  int r = blockIdx.x * 4 + (threadIdx.x >> 6);   // one wave per hop-1 row
  const int* ids1 = (const int*)(ws + OFF_IDS1);
  int node = ids1[r];
  int nb = 0;
  if (lane < NS) nb = adj[node * DEG + perm2[lane]];
  float acc = 0.f;
#pragma unroll
  for (int j = 0; j < NS; ++j) {
    int nid = __shfl(nb, j, 64);
    acc += emb[(size_t)nid * EMB + lane];
  }
  ws[OFF_ME2 + (size_t)r * EMB + lane] = acc * (1.f / NS);
  ws[OFF_X1 + (size_t)r * EMB + lane] = emb[(size_t)node * EMB + lane];
}

// ---------------------------------------------------------------- K2b: layer-1 + group mean (A-stationary)
__global__ __launch_bounds__(256) void k2b_layer1(const float* __restrict__ wsc,
                                                  float* __restrict__ ws) {
  int t = threadIdx.x, b = blockIdx.x;
  bool xp = (t < 128);
  int k = t & 127;
  const float* Wt = wsc + (xp ? OFF_A1T : OFF_A1NT);
  float wa[64];
#pragma unroll
  for (int d = 0; d < 64; ++d) wa[d] = Wt[d * 128 + k];
  float bias = wsc[(xp ? OFF_C1X : OFF_C1N) + k];
  const float* Xb = wsc + (xp ? OFF_X1 : OFF_ME2);
  for (int g = 0; g < 4; ++g) {
    int i = b * 4 + g;
    float S = 0.f;
    for (int j = 0; j < NS; ++j) {
      size_t r = (size_t)i * NS + j;
      const float4* xr = (const float4*)(Xb + r * EMB);  // wave-uniform address
      float acc = bias;
#pragma unroll
      for (int q = 0; q < 16; ++q) {
        float4 v = xr[q];
        acc = fmaf(wa[4 * q + 0], v.x, acc);
        acc = fmaf(wa[4 * q + 1], v.y, acc);
        acc = fmaf(wa[4 * q + 2], v.z, acc);
        acc = fmaf(wa[4 * q + 3], v.w, acc);
      }
      S += fmaxf(acc, 0.f);   // relu, then accumulate group mean
    }
    ws[OFF_MH1 + (size_t)i * 256 + t] = S * (1.f / NS);
  }
}

// ---------------------------------------------------------------- K3a: g0 = relu(meanE1 @ A1n^T + c1n)
__global__ __launch_bounds__(256) void k3a_g0(const float* __restrict__ wsc,
                                              float* __restrict__ ws) {
  int t = threadIdx.x, b = blockIdx.x;
  int k = t & 127, half = t >> 7;
  float wa[64];
#pragma unroll
  for (int d = 0; d < 64; ++d) wa[d] = wsc[OFF_A1NT + d * 128 + k];
  float bias = wsc[OFF_C1N + k];
  for (int it = 0; it < 4; ++it) {
    int i = b * 8 + it * 2 + half;
    const float4* xr = (const float4*)(wsc + OFF_ME1 + i * EMB);
    float acc = bias;
#pragma unroll
    for (int q = 0; q < 16; ++q) {
      float4 v = xr[q];
      acc = fmaf(wa[4 * q + 0], v.x, acc);
      acc = fmaf(wa[4 * q + 1], v.y, acc);
      acc = fmaf(wa[4 * q + 2], v.z, acc);
      acc = fmaf(wa[4 * q + 3], v.w, acc);
    }
    ws[OFF_G0 + i * 128 + k] = fmaxf(acc, 0.f);
  }
}

// ---------------------------------------------------------------- K3b: layer-2 + normalize + fc
__global__ __launch_bounds__(384) void k3b_final(const float* __restrict__ wsc,
                                                 const float* __restrict__ fcW,
                                                 const float* __restrict__ fcb,
                                                 float* __restrict__ out) {
  int t = threadIdx.x, b = blockIdx.x;
  int role = t >> 7;   // 0: part1 (w2xB), 1: part2 low half, 2: part2 high half
  int k = t & 127;
  const float* Wt = wsc + (role == 0 ? OFF_W2XBT : (role == 1 ? OFF_W2NLO : OFF_W2NHI));
  float wreg[128];
#pragma unroll
  for (int d = 0; d < 128; ++d) wreg[d] = Wt[d * 128 + k];
  float v0k = (role == 0) ? wsc[OFF_V0 + k] : 0.f;
  float fcw = (t < 256) ? fcW[t] : 0.f;
  float fcbv = fcb[0];
  __shared__ float partB[128];
  __shared__ float redN[6], redD[6];
  for (int it = 0; it < 8; ++it) {
    int i = b * 8 + it;
    const float* xbase;
    if (role == 0)      xbase = wsc + OFF_G0 + (size_t)i * 128;
    else if (role == 1) xbase = wsc + OFF_MH1 + (size_t)i * 256;
    else                xbase = wsc + OFF_MH1 + (size_t)i * 256 + 128;
    float acc = v0k;
    const float4* x4 = (const float4*)xbase;
#pragma unroll
    for (int q = 0; q < 32; ++q) {
      float4 v = x4[q];
      acc = fmaf(wreg[4 * q + 0], v.x, acc);
      acc = fmaf(wreg[4 * q + 1], v.y, acc);
      acc = fmaf(wreg[4 * q + 2], v.z, acc);
      acc = fmaf(wreg[4 * q + 3], v.w, acc);
    }
    if (role == 2) partB[k] = acc;
    __syncthreads();
    float y = 0.f;
    if (role == 0)      y = acc;
    else if (role == 1) y = acc + partB[k];
    float n2 = y * y, dt = y * fcw;
#pragma unroll
    for (int off = 32; off > 0; off >>= 1) {
      n2 += __shfl_down(n2, off, 64);
      dt += __shfl_down(dt, off, 64);
    }
    int w = t >> 6;
    if ((t & 63) == 0) { redN[w] = n2; redD[w] = dt; }
    __syncthreads();
    if (t == 0) {
      float N = 0.f, D = 0.f;
#pragma unroll
      for (int ww = 0; ww < 6; ++ww) { N += redN[ww]; D += redD[ww]; }
      out[i] = D / fmaxf(sqrtf(N), 1e-12f) + fcbv;
    }
    __syncthreads();
  }
}

// ----------------------------------------------------------------
extern "C" void kernel_launch(void* const* d_in, const int* in_sizes, int n_in,
                              void* d_out, int out_size, void* d_ws, size_t ws_size,
                              hipStream_t stream) {
  const float* emb   = (const float*)d_in[0];
  const float* prepW = (const float*)d_in[1];
  const float* prepb = (const float*)d_in[2];
  const float* w1x   = (const float*)d_in[3];
  const float* w1n   = (const float*)d_in[4];
  const float* w2x   = (const float*)d_in[5];
  const float* w2n   = (const float*)d_in[6];
  const float* fcW   = (const float*)d_in[7];
  const float* fcb   = (const float*)d_in[8];
  const int* ids     = (const int*)d_in[9];
  const int* adj     = (const int*)d_in[10];
  const int* perm1   = (const int*)d_in[11];
  const int* perm2   = (const int*)d_in[12];
  float* ws  = (float*)d_ws;
  float* out = (float*)d_out;

  hipLaunchKernelGGL(k0_prep, dim3(4), dim3(256), 0, stream,
                     emb, prepW, prepb, w1x, w1n, w2x, w2n, ws);
  hipLaunchKernelGGL(k1_hop1, dim3(BATCH / 4), dim3(256), 0, stream,
                     ids, adj, perm1, emb, ws);
  hipLaunchKernelGGL(k2a_hop2, dim3(BATCH * NS / 4), dim3(256), 0, stream,
                     adj, perm2, emb, ws);
  hipLaunchKernelGGL(k2b_layer1, dim3(BATCH * NS / 100), dim3(256), 0, stream,
                     ws, ws);
  hipLaunchKernelGGL(k3a_g0, dim3(BATCH / 8), dim3(256), 0, stream, ws, ws);
  hipLaunchKernelGGL(k3b_final, dim3(BATCH / 8), dim3(384), 0, stream,
                     ws, fcW, fcb, out);
}

// Round 2
// 881.738 us; speedup vs baseline: 1.0116x; 1.0116x over previous
//
#include <hip/hip_runtime.h>
#include <math.h>

#define NN    1000000
#define DEG   64
#define BATCH 4096
#define NS    25
#define EMB   64
#define HD    128

// workspace layout (float offsets)
#define OFF_A1     0            // 128x64   A1  = w1x@prepW   (row-major [k][d])
#define OFF_A1N    8192         // 128x64   A1n = w1n@prepW
#define OFF_W2XB   16384        // 128x128  w2x[:,128:]  (row-major [k][d])
#define OFF_W2NLO  32768        // 128x128  w2n[:,:128]
#define OFF_W2NHI  49152        // 128x128  w2n[:,128:]
#define OFF_C1X    65536        // 128
#define OFF_C1N    65664        // 128
#define OFF_V0     65792        // 128
#define OFF_IDS1   66560        // int32 region, 102400 ids
#define OFF_ME1    168960       // 4096x64   meanE1
#define OFF_X1     431104       // 102400x64 E[ids1]
#define OFF_ME2    6984704      // 102400x64 meanE2
#define OFF_MH1    13538304     // 4096x256  meanH1
#define OFF_G0     14586880     // 4096x128  g0
// total 15111168 floats = ~60.4 MB

// ---- named-register weight tile: 16 float4 = 64 weights, guaranteed VGPRs ----
#define WDECL(P) float4 P##0,P##1,P##2,P##3,P##4,P##5,P##6,P##7,P##8,P##9,P##10,P##11,P##12,P##13,P##14,P##15;
#define WLOAD(P, SRC) { const float4* _w = (const float4*)(SRC); \
  P##0=_w[0];  P##1=_w[1];  P##2=_w[2];  P##3=_w[3]; \
  P##4=_w[4];  P##5=_w[5];  P##6=_w[6];  P##7=_w[7]; \
  P##8=_w[8];  P##9=_w[9];  P##10=_w[10];P##11=_w[11]; \
  P##12=_w[12];P##13=_w[13];P##14=_w[14];P##15=_w[15]; }
#define FMA4(WQ, V, a0,a1,a2,a3) { a0=fmaf(WQ.x,(V).x,a0); a1=fmaf(WQ.y,(V).y,a1); \
                                   a2=fmaf(WQ.z,(V).z,a2); a3=fmaf(WQ.w,(V).w,a3); }
// 64-elem dot with 4 independent accumulator chains
#define DOT64(P, XPTR, a0,a1,a2,a3) { const float4* _x=(const float4*)(XPTR); float4 _v; \
  _v=_x[0];  FMA4(P##0,_v,a0,a1,a2,a3)  _v=_x[1];  FMA4(P##1,_v,a0,a1,a2,a3) \
  _v=_x[2];  FMA4(P##2,_v,a0,a1,a2,a3)  _v=_x[3];  FMA4(P##3,_v,a0,a1,a2,a3) \
  _v=_x[4];  FMA4(P##4,_v,a0,a1,a2,a3)  _v=_x[5];  FMA4(P##5,_v,a0,a1,a2,a3) \
  _v=_x[6];  FMA4(P##6,_v,a0,a1,a2,a3)  _v=_x[7];  FMA4(P##7,_v,a0,a1,a2,a3) \
  _v=_x[8];  FMA4(P##8,_v,a0,a1,a2,a3)  _v=_x[9];  FMA4(P##9,_v,a0,a1,a2,a3) \
  _v=_x[10]; FMA4(P##10,_v,a0,a1,a2,a3) _v=_x[11]; FMA4(P##11,_v,a0,a1,a2,a3) \
  _v=_x[12]; FMA4(P##12,_v,a0,a1,a2,a3) _v=_x[13]; FMA4(P##13,_v,a0,a1,a2,a3) \
  _v=_x[14]; FMA4(P##14,_v,a0,a1,a2,a3) _v=_x[15]; FMA4(P##15,_v,a0,a1,a2,a3) }

// ---------------------------------------------------------------- K0: tiny precompute
__global__ void k0_prep(const float* __restrict__ emb, const float* __restrict__ prepW,
                        const float* __restrict__ prepb,
                        const float* __restrict__ w1x, const float* __restrict__ w1n,
                        const float* __restrict__ w2x, const float* __restrict__ w2n,
                        float* __restrict__ ws) {
  int t = threadIdx.x;
  int b = blockIdx.x;
  if (b == 0 || b == 1) {
    // A = W @ prep_W  (row-major [k][d]), c = W @ prep_b
    const float* W = (b == 0) ? w1x : w1n;
    float* A = ws + ((b == 0) ? OFF_A1 : OFF_A1N);
    float* c = ws + ((b == 0) ? OFF_C1X : OFF_C1N);
    for (int idx = t; idx < 128 * 64; idx += 256) {
      int k = idx >> 6, d = idx & 63;
      float s = 0.f;
      for (int a = 0; a < 64; ++a) s += W[k * 64 + a] * prepW[a * 64 + d];
      A[k * 64 + d] = s;
    }
    if (t < 128) {
      float s = 0.f;
      for (int a = 0; a < 64; ++a) s += W[t * 64 + a] * prepb[a];
      c[t] = s;
    }
  } else if (b == 2) {
    // layer-2 weight submatrix copies (row-major [k][d])
    for (int idx = t; idx < 128 * 128; idx += 256) {
      int k = idx >> 7, d = idx & 127;
      ws[OFF_W2XB  + k * 128 + d] = w2x[k * 256 + 128 + d];
      ws[OFF_W2NLO + k * 128 + d] = w2n[k * 256 + d];
      ws[OFF_W2NHI + k * 128 + d] = w2n[k * 256 + 128 + d];
    }
  } else {
    // e0 = E[NN] @ prepW^T + prepb ; u = relu(e0 @ w1x^T) ; v0 = u @ w2x[:,:128]^T
    __shared__ float e0[64], u[128];
    if (t < 64) {
      float s = prepb[t];
      for (int d = 0; d < 64; ++d) s += emb[(size_t)NN * 64 + d] * prepW[t * 64 + d];
      e0[t] = s;
    }
    __syncthreads();
    if (t < 128) {
      float s = 0.f;
      for (int a = 0; a < 64; ++a) s += w1x[t * 64 + a] * e0[a];
      u[t] = fmaxf(s, 0.f);
    }
    __syncthreads();
    if (t < 128) {
      float s = 0.f;
      for (int k = 0; k < 128; ++k) s += u[k] * w2x[t * 256 + k];
      ws[OFF_V0 + t] = s;
    }
  }
}

// ---------------------------------------------------------------- K1: hop-1 sample + meanE1
__global__ void k1_hop1(const int* __restrict__ ids, const int* __restrict__ adj,
                        const int* __restrict__ perm1, const float* __restrict__ emb,
                        float* __restrict__ ws) {
  int lane = threadIdx.x & 63;
  int i = blockIdx.x * 4 + (threadIdx.x >> 6);   // one wave per batch row
  int node = ids[i];
  int nb = 0;
  if (lane < NS) nb = adj[node * DEG + perm1[lane]];
  float acc = 0.f;
#pragma unroll
  for (int j = 0; j < NS; ++j) {
    int nid = __shfl(nb, j, 64);
    acc += emb[(size_t)nid * EMB + lane];
  }
  ws[OFF_ME1 + i * EMB + lane] = acc * (1.f / NS);
  int* ids1 = (int*)(ws + OFF_IDS1);
  if (lane < NS) ids1[i * NS + lane] = nb;
}

// ---------------------------------------------------------------- K2a: hop-2 gather
__global__ void k2a_hop2(const int* __restrict__ adj, const int* __restrict__ perm2,
                         const float* __restrict__ emb, float* __restrict__ ws) {
  int lane = threadIdx.x & 63;
  int r = blockIdx.x * 4 + (threadIdx.x >> 6);   // one wave per hop-1 row
  const int* ids1 = (const int*)(ws + OFF_IDS1);
  int node = ids1[r];
  int nb = 0;
  if (lane < NS) nb = adj[node * DEG + perm2[lane]];
  float acc = 0.f;
#pragma unroll
  for (int j = 0; j < NS; ++j) {
    int nid = __shfl(nb, j, 64);
    acc += emb[(size_t)nid * EMB + lane];
  }
  ws[OFF_ME2 + (size_t)r * EMB + lane] = acc * (1.f / NS);
  ws[OFF_X1 + (size_t)r * EMB + lane] = emb[(size_t)node * EMB + lane];
}

// ---------------------------------------------------------------- K2b: layer-1 + group mean
// thread t: output k=t&127, x-branch if t<128 else n-branch. Weights in 16 named float4.
__global__ __launch_bounds__(256) void k2b_layer1(const float* __restrict__ wsc,
                                                  float* __restrict__ ws) {
  int t = threadIdx.x, b = blockIdx.x;
  bool xp = (t < 128);
  int k = t & 127;
  WDECL(W)
  WLOAD(W, wsc + (xp ? OFF_A1 : OFF_A1N) + k * 64)
  float bias = wsc[(xp ? OFF_C1X : OFF_C1N) + k];
  const float* Xb = wsc + (xp ? OFF_X1 : OFF_ME2);
  for (int g = 0; g < 4; ++g) {
    int i = b * 4 + g;
    float S = 0.f;
    for (int j = 0; j < NS; ++j) {
      const float* xr = Xb + ((size_t)i * NS + j) * EMB;   // wave-uniform address
      float a0 = bias, a1 = 0.f, a2 = 0.f, a3 = 0.f;
      DOT64(W, xr, a0, a1, a2, a3)
      S += fmaxf((a0 + a1) + (a2 + a3), 0.f);              // relu, then group mean
    }
    ws[OFF_MH1 + (size_t)i * 256 + t] = S * (1.f / NS);
  }
}

// ---------------------------------------------------------------- K3a: g0 = relu(meanE1 @ A1n^T + c1n)
__global__ __launch_bounds__(256) void k3a_g0(const float* __restrict__ wsc,
                                              float* __restrict__ ws) {
  int t = threadIdx.x, b = blockIdx.x;
  int k = t & 127, half = t >> 7;
  WDECL(W)
  WLOAD(W, wsc + OFF_A1N + k * 64)
  float bias = wsc[OFF_C1N + k];
  for (int it = 0; it < 4; ++it) {
    int i = b * 8 + it * 2 + half;
    const float* xr = wsc + OFF_ME1 + i * EMB;
    float a0 = bias, a1 = 0.f, a2 = 0.f, a3 = 0.f;
    DOT64(W, xr, a0, a1, a2, a3)
    ws[OFF_G0 + i * 128 + k] = fmaxf((a0 + a1) + (a2 + a3), 0.f);
  }
}

// ---------------------------------------------------------------- K3b: layer-2 + normalize + fc
// 384 threads, 3 roles of 128: role0 = y[:128] (v0 + g0@w2xB^T),
// role1/2 = the 256-dot for y[128:] split in two 128-chunks.
__global__ __launch_bounds__(384) void k3b_final(const float* __restrict__ wsc,
                                                 const float* __restrict__ fcW,
                                                 const float* __restrict__ fcb,
                                                 float* __restrict__ out) {
  int t = threadIdx.x, b = blockIdx.x;
  int role = t >> 7;
  int k = t & 127;
  const float* Wrow = wsc + (role == 0 ? OFF_W2XB : (role == 1 ? OFF_W2NLO : OFF_W2NHI))
                    + k * 128;
  WDECL(W)                       // first 64 weights
  WDECL(X)                       // second 64 weights
  WLOAD(W, Wrow)
  WLOAD(X, Wrow + 64)
  float v0k = (role == 0) ? wsc[OFF_V0 + k] : 0.f;
  float fcw = (t < 256) ? fcW[t] : 0.f;
  float fcbv = fcb[0];
  __shared__ float partB[128];
  __shared__ float redN[6], redD[6];
  for (int it = 0; it < 8; ++it) {
    int i = b * 8 + it;
    const float* xbase;
    if (role == 0)      xbase = wsc + OFF_G0 + (size_t)i * 128;
    else if (role == 1) xbase = wsc + OFF_MH1 + (size_t)i * 256;
    else                xbase = wsc + OFF_MH1 + (size_t)i * 256 + 128;
    float a0 = v0k, a1 = 0.f, a2 = 0.f, a3 = 0.f;
    DOT64(W, xbase, a0, a1, a2, a3)
    DOT64(X, xbase + 64, a0, a1, a2, a3)
    float acc = (a0 + a1) + (a2 + a3);
    if (role == 2) partB[k] = acc;
    __syncthreads();
    float y = 0.f;
    if (role == 0)      y = acc;
    else if (role == 1) y = acc + partB[k];
    float n2 = y * y, dt = y * fcw;
#pragma unroll
    for (int off = 32; off > 0; off >>= 1) {
      n2 += __shfl_down(n2, off, 64);
      dt += __shfl_down(dt, off, 64);
    }
    int w = t >> 6;
    if ((t & 63) == 0) { redN[w] = n2; redD[w] = dt; }
    __syncthreads();
    if (t == 0) {
      float N = 0.f, D = 0.f;
#pragma unroll
      for (int ww = 0; ww < 6; ++ww) { N += redN[ww]; D += redD[ww]; }
      out[i] = D / fmaxf(sqrtf(N), 1e-12f) + fcbv;
    }
    __syncthreads();
  }
}

// ----------------------------------------------------------------
extern "C" void kernel_launch(void* const* d_in, const int* in_sizes, int n_in,
                              void* d_out, int out_size, void* d_ws, size_t ws_size,
                              hipStream_t stream) {
  const float* emb   = (const float*)d_in[0];
  const float* prepW = (const float*)d_in[1];
  const float* prepb = (const float*)d_in[2];
  const float* w1x   = (const float*)d_in[3];
  const float* w1n   = (const float*)d_in[4];
  const float* w2x   = (const float*)d_in[5];
  const float* w2n   = (const float*)d_in[6];
  const float* fcW   = (const float*)d_in[7];
  const float* fcb   = (const float*)d_in[8];
  const int* ids     = (const int*)d_in[9];
  const int* adj     = (const int*)d_in[10];
  const int* perm1   = (const int*)d_in[11];
  const int* perm2   = (const int*)d_in[12];
  float* ws  = (float*)d_ws;
  float* out = (float*)d_out;

  hipLaunchKernelGGL(k0_prep, dim3(4), dim3(256), 0, stream,
                     emb, prepW, prepb, w1x, w1n, w2x, w2n, ws);
  hipLaunchKernelGGL(k1_hop1, dim3(BATCH / 4), dim3(256), 0, stream,
                     ids, adj, perm1, emb, ws);
  hipLaunchKernelGGL(k2a_hop2, dim3(BATCH * NS / 4), dim3(256), 0, stream,
                     adj, perm2, emb, ws);
  hipLaunchKernelGGL(k2b_layer1, dim3(BATCH * NS / 100), dim3(256), 0, stream,
                     ws, ws);
  hipLaunchKernelGGL(k3a_g0, dim3(BATCH / 8), dim3(256), 0, stream, ws, ws);
  hipLaunchKernelGGL(k3b_final, dim3(BATCH / 8), dim3(384), 0, stream,
                     ws, fcW, fcb, out);
}

// Round 3
// 877.276 us; speedup vs baseline: 1.0168x; 1.0051x over previous
//
#include <hip/hip_runtime.h>
#include <math.h>

#define NN    1000000
#define DEG   64
#define BATCH 4096
#define NS    25
#define EMB   64
#define HD    128

// workspace layout (float offsets)
#define OFF_A1     0            // 128x64   A1  = w1x@prepW   (row-major [k][d])
#define OFF_A1N    8192         // 128x64   A1n = w1n@prepW
#define OFF_W2XB   16384        // 128x128  w2x[:,128:]  (row-major [k][d])
#define OFF_W2NLO  32768        // 128x128  w2n[:,:128]
#define OFF_W2NHI  49152        // 128x128  w2n[:,128:]
#define OFF_C1X    65536        // 128
#define OFF_C1N    65664        // 128
#define OFF_V0     65792        // 128
#define OFF_IDS1   66560        // int32 region, 102400 ids
#define OFF_ME1    168960       // 4096x64   meanE1
#define OFF_MH1    13538304     // 4096x256  meanH1
#define OFF_G0     14586880     // 4096x128  g0

// ---- named-register weight tile: 16 float4 = 64 weights ----
#define WDECL(P) float4 P##0,P##1,P##2,P##3,P##4,P##5,P##6,P##7,P##8,P##9,P##10,P##11,P##12,P##13,P##14,P##15;
#define WLOAD(P, SRC) { const float4* _w = (const float4*)(SRC); \
  P##0=_w[0];  P##1=_w[1];  P##2=_w[2];  P##3=_w[3]; \
  P##4=_w[4];  P##5=_w[5];  P##6=_w[6];  P##7=_w[7]; \
  P##8=_w[8];  P##9=_w[9];  P##10=_w[10];P##11=_w[11]; \
  P##12=_w[12];P##13=_w[13];P##14=_w[14];P##15=_w[15]; }
#define FMA4(WQ, V, a0,a1,a2,a3) { a0=fmaf(WQ.x,(V).x,a0); a1=fmaf(WQ.y,(V).y,a1); \
                                   a2=fmaf(WQ.z,(V).z,a2); a3=fmaf(WQ.w,(V).w,a3); }
#define DOT64(P, XPTR, a0,a1,a2,a3) { const float4* _x=(const float4*)(XPTR); float4 _v; \
  _v=_x[0];  FMA4(P##0,_v,a0,a1,a2,a3)  _v=_x[1];  FMA4(P##1,_v,a0,a1,a2,a3) \
  _v=_x[2];  FMA4(P##2,_v,a0,a1,a2,a3)  _v=_x[3];  FMA4(P##3,_v,a0,a1,a2,a3) \
  _v=_x[4];  FMA4(P##4,_v,a0,a1,a2,a3)  _v=_x[5];  FMA4(P##5,_v,a0,a1,a2,a3) \
  _v=_x[6];  FMA4(P##6,_v,a0,a1,a2,a3)  _v=_x[7];  FMA4(P##7,_v,a0,a1,a2,a3) \
  _v=_x[8];  FMA4(P##8,_v,a0,a1,a2,a3)  _v=_x[9];  FMA4(P##9,_v,a0,a1,a2,a3) \
  _v=_x[10]; FMA4(P##10,_v,a0,a1,a2,a3) _v=_x[11]; FMA4(P##11,_v,a0,a1,a2,a3) \
  _v=_x[12]; FMA4(P##12,_v,a0,a1,a2,a3) _v=_x[13]; FMA4(P##13,_v,a0,a1,a2,a3) \
  _v=_x[14]; FMA4(P##14,_v,a0,a1,a2,a3) _v=_x[15]; FMA4(P##15,_v,a0,a1,a2,a3) }

// ---------------------------------------------------------------- K0: tiny precompute
__global__ void k0_prep(const float* __restrict__ emb, const float* __restrict__ prepW,
                        const float* __restrict__ prepb,
                        const float* __restrict__ w1x, const float* __restrict__ w1n,
                        const float* __restrict__ w2x, const float* __restrict__ w2n,
                        float* __restrict__ ws) {
  int t = threadIdx.x;
  int b = blockIdx.x;
  if (b == 0 || b == 1) {
    const float* W = (b == 0) ? w1x : w1n;
    float* A = ws + ((b == 0) ? OFF_A1 : OFF_A1N);
    float* c = ws + ((b == 0) ? OFF_C1X : OFF_C1N);
    for (int idx = t; idx < 128 * 64; idx += 256) {
      int k = idx >> 6, d = idx & 63;
      float s = 0.f;
      for (int a = 0; a < 64; ++a) s += W[k * 64 + a] * prepW[a * 64 + d];
      A[k * 64 + d] = s;
    }
    if (t < 128) {
      float s = 0.f;
      for (int a = 0; a < 64; ++a) s += W[t * 64 + a] * prepb[a];
      c[t] = s;
    }
  } else if (b == 2) {
    for (int idx = t; idx < 128 * 128; idx += 256) {
      int k = idx >> 7, d = idx & 127;
      ws[OFF_W2XB  + k * 128 + d] = w2x[k * 256 + 128 + d];
      ws[OFF_W2NLO + k * 128 + d] = w2n[k * 256 + d];
      ws[OFF_W2NHI + k * 128 + d] = w2n[k * 256 + 128 + d];
    }
  } else {
    __shared__ float e0[64], u[128];
    if (t < 64) {
      float s = prepb[t];
      for (int d = 0; d < 64; ++d) s += emb[(size_t)NN * 64 + d] * prepW[t * 64 + d];
      e0[t] = s;
    }
    __syncthreads();
    if (t < 128) {
      float s = 0.f;
      for (int a = 0; a < 64; ++a) s += w1x[t * 64 + a] * e0[a];
      u[t] = fmaxf(s, 0.f);
    }
    __syncthreads();
    if (t < 128) {
      float s = 0.f;
      for (int k = 0; k < 128; ++k) s += u[k] * w2x[t * 256 + k];
      ws[OFF_V0 + t] = s;
    }
  }
}

// ---------------------------------------------------------------- K1: hop-1 sample + meanE1
__global__ __launch_bounds__(256, 2) void k1_hop1(const int* __restrict__ ids,
                                                  const int* __restrict__ adj,
                                                  const int* __restrict__ perm1,
                                                  const float* __restrict__ emb,
                                                  float* __restrict__ ws) {
  int lane = threadIdx.x & 63;
  int i = blockIdx.x * 4 + (threadIdx.x >> 6);   // one wave per batch row
  int node = ids[i];
  int p1 = (lane < NS) ? perm1[lane] : 0;
  int nb = adj[(size_t)node * DEG + p1];
  float acc = 0.f;
#pragma unroll
  for (int j = 0; j < NS; ++j) {
    int nid = __shfl(nb, j, 64);
    acc += emb[(size_t)nid * EMB + lane];
  }
  ws[OFF_ME1 + i * EMB + lane] = acc * (1.f / NS);
  int* ids1 = (int*)(ws + OFF_IDS1);
  if (lane < NS) ids1[i * NS + lane] = nb;
}

// ---------------------------------------------------------------- K2 fused: hop-2 gather + layer-1 + group mean
// one block per batch row i. Gather 25x25 hop-2 rows -> meanE2 in LDS, X1 rows in LDS.
// Then thread t (k=t&127): weights resident in VGPRs, x from LDS broadcast.
__global__ __launch_bounds__(256, 2) void k2_fused(const int* __restrict__ adj,
                                                   const int* __restrict__ perm2,
                                                   const float* __restrict__ emb,
                                                   const float* __restrict__ wsc,
                                                   float* __restrict__ ws) {
  __shared__ __align__(16) float X1t[NS][64];
  __shared__ __align__(16) float ME2t[NS][64];
  int t = threadIdx.x, i = blockIdx.x;
  int lane = t & 63, w = t >> 6;
  bool xp = (t < 128);
  int k = t & 127;
  // weights resident (hoisted; launch_bounds(256,2) gives 256-VGPR headroom)
  WDECL(W)
  WLOAD(W, wsc + (xp ? OFF_A1 : OFF_A1N) + k * 64)
  float bias = wsc[(xp ? OFF_C1X : OFF_C1N) + k];

  const int* ids1 = (const int*)(wsc + OFF_IDS1);
  int p2 = (lane < NS) ? perm2[lane] : 0;
  for (int r = w; r < NS; r += 4) {        // wave w handles hop-1 rows r, r+4, ...
    int node = ids1[i * NS + r];
    int nb = adj[(size_t)node * DEG + p2];
    float acc = 0.f;
#pragma unroll
    for (int j = 0; j < NS; ++j) {
      int nid = __shfl(nb, j, 64);
      acc += emb[(size_t)nid * EMB + lane];
    }
    ME2t[r][lane] = acc * (1.f / NS);
    X1t[r][lane] = emb[(size_t)node * EMB + lane];
  }
  __syncthreads();

  float S = 0.f;
  const float* Xt = xp ? &X1t[0][0] : &ME2t[0][0];
  for (int r = 0; r < NS; ++r) {
    float a0 = bias, a1 = 0.f, a2 = 0.f, a3 = 0.f;
    DOT64(W, Xt + r * 64, a0, a1, a2, a3)
    S += fmaxf((a0 + a1) + (a2 + a3), 0.f);
  }
  ws[OFF_MH1 + (size_t)i * 256 + t] = S * (1.f / NS);
}

// ---------------------------------------------------------------- K3a: g0 = relu(meanE1 @ A1n^T + c1n)
__global__ __launch_bounds__(256, 2) void k3a_g0(const float* __restrict__ wsc,
                                                 float* __restrict__ ws) {
  __shared__ __align__(16) float me1[16][64];
  int t = threadIdx.x, b = blockIdx.x;     // 256 blocks x 16 rows
  int k = t & 127, half = t >> 7;
  WDECL(W)
  WLOAD(W, wsc + OFF_A1N + k * 64)
  float bias = wsc[OFF_C1N + k];
  // stage 16 rows (1024 floats) with 256 float4 loads, coalesced
  const float4* src = (const float4*)(wsc + OFF_ME1 + b * 16 * 64);
  ((float4*)me1)[t] = src[t];
  __syncthreads();
  for (int rr = 0; rr < 8; ++rr) {
    int r = rr * 2 + half;
    float a0 = bias, a1 = 0.f, a2 = 0.f, a3 = 0.f;
    DOT64(W, &me1[r][0], a0, a1, a2, a3)
    ws[OFF_G0 + (size_t)(b * 16 + r) * 128 + k] = fmaxf((a0 + a1) + (a2 + a3), 0.f);
  }
}

// ---------------------------------------------------------------- K3b: layer-2 + normalize + fc
// 384 threads, 3 roles of 128. x staged in LDS (exactly 384 floats/row).
__global__ __launch_bounds__(384, 1) void k3b_final(const float* __restrict__ wsc,
                                                    const float* __restrict__ fcW,
                                                    const float* __restrict__ fcb,
                                                    float* __restrict__ out) {
  __shared__ __align__(16) float xrow[384];   // [0:128) g0 row, [128:384) mh1 row
  __shared__ float partB[128];
  __shared__ float redN[6], redD[6];
  int t = threadIdx.x, b = blockIdx.x;
  int role = t >> 7;
  int k = t & 127;
  const float* Wrow = wsc + (role == 0 ? OFF_W2XB : (role == 1 ? OFF_W2NLO : OFF_W2NHI))
                    + k * 128;
  WDECL(W)
  WDECL(X)
  WLOAD(W, Wrow)
  WLOAD(X, Wrow + 64)
  float v0k = (role == 0) ? wsc[OFF_V0 + k] : 0.f;
  float fcw = (t < 256) ? fcW[t] : 0.f;
  float fcbv = fcb[0];
  for (int it = 0; it < 8; ++it) {
    int i = b * 8 + it;
    xrow[t] = (t < 128) ? wsc[OFF_G0 + (size_t)i * 128 + t]
                        : wsc[OFF_MH1 + (size_t)i * 256 + (t - 128)];
    __syncthreads();
    const float* xbase = (role == 0) ? xrow : (role == 1 ? xrow + 128 : xrow + 256);
    float a0 = v0k, a1 = 0.f, a2 = 0.f, a3 = 0.f;
    DOT64(W, xbase, a0, a1, a2, a3)
    DOT64(X, xbase + 64, a0, a1, a2, a3)
    float acc = (a0 + a1) + (a2 + a3);
    if (role == 2) partB[k] = acc;
    __syncthreads();
    float y = 0.f;
    if (role == 0)      y = acc;
    else if (role == 1) y = acc + partB[k];
    float n2 = y * y, dt = y * fcw;
#pragma unroll
    for (int off = 32; off > 0; off >>= 1) {
      n2 += __shfl_down(n2, off, 64);
      dt += __shfl_down(dt, off, 64);
    }
    int w = t >> 6;
    if ((t & 63) == 0) { redN[w] = n2; redD[w] = dt; }
    __syncthreads();
    if (t == 0) {
      float N = 0.f, D = 0.f;
#pragma unroll
      for (int ww = 0; ww < 6; ++ww) { N += redN[ww]; D += redD[ww]; }
      out[i] = D / fmaxf(sqrtf(N), 1e-12f) + fcbv;
    }
    __syncthreads();
  }
}

// ----------------------------------------------------------------
extern "C" void kernel_launch(void* const* d_in, const int* in_sizes, int n_in,
                              void* d_out, int out_size, void* d_ws, size_t ws_size,
                              hipStream_t stream) {
  const float* emb   = (const float*)d_in[0];
  const float* prepW = (const float*)d_in[1];
  const float* prepb = (const float*)d_in[2];
  const float* w1x   = (const float*)d_in[3];
  const float* w1n   = (const float*)d_in[4];
  const float* w2x   = (const float*)d_in[5];
  const float* w2n   = (const float*)d_in[6];
  const float* fcW   = (const float*)d_in[7];
  const float* fcb   = (const float*)d_in[8];
  const int* ids     = (const int*)d_in[9];
  const int* adj     = (const int*)d_in[10];
  const int* perm1   = (const int*)d_in[11];
  const int* perm2   = (const int*)d_in[12];
  float* ws  = (float*)d_ws;
  float* out = (float*)d_out;

  hipLaunchKernelGGL(k0_prep, dim3(4), dim3(256), 0, stream,
                     emb, prepW, prepb, w1x, w1n, w2x, w2n, ws);
  hipLaunchKernelGGL(k1_hop1, dim3(BATCH / 4), dim3(256), 0, stream,
                     ids, adj, perm1, emb, ws);
  hipLaunchKernelGGL(k2_fused, dim3(BATCH), dim3(256), 0, stream,
                     adj, perm2, emb, ws, ws);
  hipLaunchKernelGGL(k3a_g0, dim3(BATCH / 16), dim3(256), 0, stream, ws, ws);
  hipLaunchKernelGGL(k3b_final, dim3(BATCH / 8), dim3(384), 0, stream,
                     ws, fcW, fcb, out);
}

// Round 4
// 779.973 us; speedup vs baseline: 1.1436x; 1.1248x over previous
//
#include <hip/hip_runtime.h>
#include <math.h>

#define NN    1000000
#define DEG   64
#define BATCH 4096
#define NS    25
#define EMB   64
#define HD    128

// workspace layout (float offsets)
#define OFF_A1     0            // 128x64   A1  = w1x@prepW   (row-major [k][d])
#define OFF_A1N    8192         // 128x64   A1n = w1n@prepW
#define OFF_W2XB   16384        // 128x128  w2x[:,128:]  (row-major [k][d])
#define OFF_W2NLO  32768        // 128x128  w2n[:,:128]
#define OFF_W2NHI  49152        // 128x128  w2n[:,128:]
#define OFF_C1X    65536        // 128
#define OFF_C1N    65664        // 128
#define OFF_V0     65792        // 128
#define OFF_MH1    13538304     // 4096x256  meanH1
#define OFF_G0     14586880     // 4096x128  g0

// ---- named-register weight tile: 16 float4 = 64 weights ----
#define WDECL(P) float4 P##0,P##1,P##2,P##3,P##4,P##5,P##6,P##7,P##8,P##9,P##10,P##11,P##12,P##13,P##14,P##15;
#define WLOAD(P, SRC) { const float4* _w = (const float4*)(SRC); \
  P##0=_w[0];  P##1=_w[1];  P##2=_w[2];  P##3=_w[3]; \
  P##4=_w[4];  P##5=_w[5];  P##6=_w[6];  P##7=_w[7]; \
  P##8=_w[8];  P##9=_w[9];  P##10=_w[10];P##11=_w[11]; \
  P##12=_w[12];P##13=_w[13];P##14=_w[14];P##15=_w[15]; }
// pin: opaque asm prevents rematerialization/sinking of the weight loads
#define PIN4(Q) asm volatile("" : "+v"(Q.x), "+v"(Q.y), "+v"(Q.z), "+v"(Q.w));
#define WPIN(P) { PIN4(P##0) PIN4(P##1) PIN4(P##2) PIN4(P##3) PIN4(P##4) PIN4(P##5) \
  PIN4(P##6) PIN4(P##7) PIN4(P##8) PIN4(P##9) PIN4(P##10) PIN4(P##11) PIN4(P##12) \
  PIN4(P##13) PIN4(P##14) PIN4(P##15) }
#define FMA4(WQ, V, a0,a1,a2,a3) { a0=fmaf(WQ.x,(V).x,a0); a1=fmaf(WQ.y,(V).y,a1); \
                                   a2=fmaf(WQ.z,(V).z,a2); a3=fmaf(WQ.w,(V).w,a3); }
#define DOT64(P, XPTR, a0,a1,a2,a3) { const float4* _x=(const float4*)(XPTR); float4 _v; \
  _v=_x[0];  FMA4(P##0,_v,a0,a1,a2,a3)  _v=_x[1];  FMA4(P##1,_v,a0,a1,a2,a3) \
  _v=_x[2];  FMA4(P##2,_v,a0,a1,a2,a3)  _v=_x[3];  FMA4(P##3,_v,a0,a1,a2,a3) \
  _v=_x[4];  FMA4(P##4,_v,a0,a1,a2,a3)  _v=_x[5];  FMA4(P##5,_v,a0,a1,a2,a3) \
  _v=_x[6];  FMA4(P##6,_v,a0,a1,a2,a3)  _v=_x[7];  FMA4(P##7,_v,a0,a1,a2,a3) \
  _v=_x[8];  FMA4(P##8,_v,a0,a1,a2,a3)  _v=_x[9];  FMA4(P##9,_v,a0,a1,a2,a3) \
  _v=_x[10]; FMA4(P##10,_v,a0,a1,a2,a3) _v=_x[11]; FMA4(P##11,_v,a0,a1,a2,a3) \
  _v=_x[12]; FMA4(P##12,_v,a0,a1,a2,a3) _v=_x[13]; FMA4(P##13,_v,a0,a1,a2,a3) \
  _v=_x[14]; FMA4(P##14,_v,a0,a1,a2,a3) _v=_x[15]; FMA4(P##15,_v,a0,a1,a2,a3) }

// ---------------------------------------------------------------- K0: tiny precompute
__global__ void k0_prep(const float* __restrict__ emb, const float* __restrict__ prepW,
                        const float* __restrict__ prepb,
                        const float* __restrict__ w1x, const float* __restrict__ w1n,
                        const float* __restrict__ w2x, const float* __restrict__ w2n,
                        float* __restrict__ ws) {
  int t = threadIdx.x;
  int b = blockIdx.x;
  if (b == 0 || b == 1) {
    const float* W = (b == 0) ? w1x : w1n;
    float* A = ws + ((b == 0) ? OFF_A1 : OFF_A1N);
    float* c = ws + ((b == 0) ? OFF_C1X : OFF_C1N);
    for (int idx = t; idx < 128 * 64; idx += 256) {
      int k = idx >> 6, d = idx & 63;
      float s = 0.f;
      for (int a = 0; a < 64; ++a) s += W[k * 64 + a] * prepW[a * 64 + d];
      A[k * 64 + d] = s;
    }
    if (t < 128) {
      float s = 0.f;
      for (int a = 0; a < 64; ++a) s += W[t * 64 + a] * prepb[a];
      c[t] = s;
    }
  } else if (b == 2) {
    for (int idx = t; idx < 128 * 128; idx += 256) {
      int k = idx >> 7, d = idx & 127;
      ws[OFF_W2XB  + k * 128 + d] = w2x[k * 256 + 128 + d];
      ws[OFF_W2NLO + k * 128 + d] = w2n[k * 256 + d];
      ws[OFF_W2NHI + k * 128 + d] = w2n[k * 256 + 128 + d];
    }
  } else {
    __shared__ float e0[64], u[128];
    if (t < 64) {
      float s = prepb[t];
      for (int d = 0; d < 64; ++d) s += emb[(size_t)NN * 64 + d] * prepW[t * 64 + d];
      e0[t] = s;
    }
    __syncthreads();
    if (t < 128) {
      float s = 0.f;
      for (int a = 0; a < 64; ++a) s += w1x[t * 64 + a] * e0[a];
      u[t] = fmaxf(s, 0.f);
    }
    __syncthreads();
    if (t < 128) {
      float s = 0.f;
      for (int k = 0; k < 128; ++k) s += u[k] * w2x[t * 256 + k];
      ws[OFF_V0 + t] = s;
    }
  }
}

// ---------------------------------------------------------------- K2 fused:
// hop-1 sample + hop-2 gather + layer-1 (both pairs) + group means + g0.
// One block per batch row. Waves redundantly load the hop-1 neighbor list,
// gather X1 (hop-1 rows) and ME2 (hop-2 group means) into LDS, then dot with
// VGPR-pinned weights.
__global__ __launch_bounds__(256, 3) void k2_fused(const int* __restrict__ ids,
                                                   const int* __restrict__ adj,
                                                   const int* __restrict__ perm1,
                                                   const int* __restrict__ perm2,
                                                   const float* __restrict__ emb,
                                                   const float* __restrict__ wsc,
                                                   float* __restrict__ ws) {
  __shared__ __align__(16) float X1t[NS][64];
  __shared__ __align__(16) float ME2t[NS][64];
  __shared__ __align__(16) float me1s[64];
  int t = threadIdx.x, i = blockIdx.x;
  int lane = t & 63, w = t >> 6;
  bool xp = (t < 128);
  int k = t & 127;

  // issue weight loads now; they stay in flight through the gather phase
  WDECL(W)
  WLOAD(W, wsc + (xp ? OFF_A1 : OFF_A1N) + k * 64)
  float bias = wsc[(xp ? OFF_C1X : OFF_C1N) + k];

  // hop-1: every wave loads the 25 hop-1 neighbors (redundant across waves, L1-hot)
  int root = ids[i];
  int p1 = (lane < NS) ? perm1[lane] : 0;
  int p2 = (lane < NS) ? perm2[lane] : 0;
  int nb1 = adj[(size_t)root * DEG + p1];

  // prefetch adjacency rows for my hop-1 rows (r = w, w+4, ...) to raise MLP
  int noder[7], nb2r[7];
#pragma unroll
  for (int rr = 0; rr < 7; ++rr) {
    int r = w + rr * 4;
    if (r < NS) {                       // wave-uniform predicate
      int node = __shfl(nb1, r, 64);
      noder[rr] = node;
      nb2r[rr] = adj[(size_t)node * DEG + p2];
    }
  }
  // X1 rows (also feed meanE1)
#pragma unroll
  for (int rr = 0; rr < 7; ++rr) {
    int r = w + rr * 4;
    if (r < NS) X1t[r][lane] = emb[(size_t)noder[rr] * EMB + lane];
  }
  // hop-2 gather + per-row mean
#pragma unroll
  for (int rr = 0; rr < 7; ++rr) {
    int r = w + rr * 4;
    if (r < NS) {
      float acc = 0.f;
#pragma unroll
      for (int j = 0; j < NS; ++j) {
        int nid = __shfl(nb2r[rr], j, 64);
        acc += emb[(size_t)nid * EMB + lane];
      }
      ME2t[r][lane] = acc * (1.f / NS);
    }
  }
  __syncthreads();
  // meanE1 = column means of X1t
  if (t < 64) {
    float s = 0.f;
#pragma unroll
    for (int r = 0; r < NS; ++r) s += X1t[r][t];
    me1s[t] = s * (1.f / NS);
  }
  WPIN(W)            // materialize weights in VGPRs before the dot phase
  __syncthreads();

  float S = 0.f;
  const float* Xt = xp ? &X1t[0][0] : &ME2t[0][0];
  for (int r = 0; r < NS; ++r) {
    float a0 = bias, a1 = 0.f, a2 = 0.f, a3 = 0.f;
    DOT64(W, Xt + r * 64, a0, a1, a2, a3)
    S += fmaxf((a0 + a1) + (a2 + a3), 0.f);
  }
  ws[OFF_MH1 + (size_t)i * 256 + t] = S * (1.f / NS);
  if (!xp) {         // n-branch threads also produce g0 (h0's neighbor half)
    float a0 = bias, a1 = 0.f, a2 = 0.f, a3 = 0.f;
    DOT64(W, me1s, a0, a1, a2, a3)
    ws[OFF_G0 + (size_t)i * 128 + k] = fmaxf((a0 + a1) + (a2 + a3), 0.f);
  }
}

// ---------------------------------------------------------------- K3b: layer-2 + normalize + fc
__global__ __launch_bounds__(384, 1) void k3b_final(const float* __restrict__ wsc,
                                                    const float* __restrict__ fcW,
                                                    const float* __restrict__ fcb,
                                                    float* __restrict__ out) {
  __shared__ __align__(16) float xrow[384];   // [0:128) g0 row, [128:384) mh1 row
  __shared__ float partB[128];
  __shared__ float redN[6], redD[6];
  int t = threadIdx.x, b = blockIdx.x;
  int role = t >> 7;
  int k = t & 127;
  const float* Wrow = wsc + (role == 0 ? OFF_W2XB : (role == 1 ? OFF_W2NLO : OFF_W2NHI))
                    + k * 128;
  WDECL(W)
  WDECL(X)
  WLOAD(W, Wrow)
  WLOAD(X, Wrow + 64)
  WPIN(W)
  WPIN(X)
  float v0k = (role == 0) ? wsc[OFF_V0 + k] : 0.f;
  float fcw = (t < 256) ? fcW[t] : 0.f;
  float fcbv = fcb[0];
  for (int it = 0; it < 8; ++it) {
    int i = b * 8 + it;
    xrow[t] = (t < 128) ? wsc[OFF_G0 + (size_t)i * 128 + t]
                        : wsc[OFF_MH1 + (size_t)i * 256 + (t - 128)];
    __syncthreads();
    const float* xbase = (role == 0) ? xrow : (role == 1 ? xrow + 128 : xrow + 256);
    float a0 = v0k, a1 = 0.f, a2 = 0.f, a3 = 0.f;
    DOT64(W, xbase, a0, a1, a2, a3)
    DOT64(X, xbase + 64, a0, a1, a2, a3)
    float acc = (a0 + a1) + (a2 + a3);
    if (role == 2) partB[k] = acc;
    __syncthreads();
    float y = 0.f;
    if (role == 0)      y = acc;
    else if (role == 1) y = acc + partB[k];
    float n2 = y * y, dt = y * fcw;
#pragma unroll
    for (int off = 32; off > 0; off >>= 1) {
      n2 += __shfl_down(n2, off, 64);
      dt += __shfl_down(dt, off, 64);
    }
    int w = t >> 6;
    if ((t & 63) == 0) { redN[w] = n2; redD[w] = dt; }
    __syncthreads();
    if (t == 0) {
      float N = 0.f, D = 0.f;
#pragma unroll
      for (int ww = 0; ww < 6; ++ww) { N += redN[ww]; D += redD[ww]; }
      out[i] = D / fmaxf(sqrtf(N), 1e-12f) + fcbv;
    }
    __syncthreads();
  }
}

// ----------------------------------------------------------------
extern "C" void kernel_launch(void* const* d_in, const int* in_sizes, int n_in,
                              void* d_out, int out_size, void* d_ws, size_t ws_size,
                              hipStream_t stream) {
  const float* emb   = (const float*)d_in[0];
  const float* prepW = (const float*)d_in[1];
  const float* prepb = (const float*)d_in[2];
  const float* w1x   = (const float*)d_in[3];
  const float* w1n   = (const float*)d_in[4];
  const float* w2x   = (const float*)d_in[5];
  const float* w2n   = (const float*)d_in[6];
  const float* fcW   = (const float*)d_in[7];
  const float* fcb   = (const float*)d_in[8];
  const int* ids     = (const int*)d_in[9];
  const int* adj     = (const int*)d_in[10];
  const int* perm1   = (const int*)d_in[11];
  const int* perm2   = (const int*)d_in[12];
  float* ws  = (float*)d_ws;
  float* out = (float*)d_out;

  hipLaunchKernelGGL(k0_prep, dim3(4), dim3(256), 0, stream,
                     emb, prepW, prepb, w1x, w1n, w2x, w2n, ws);
  hipLaunchKernelGGL(k2_fused, dim3(BATCH), dim3(256), 0, stream,
                     ids, adj, perm1, perm2, emb, ws, ws);
  hipLaunchKernelGGL(k3b_final, dim3(BATCH / 8), dim3(384), 0, stream,
                     ws, fcW, fcb, out);
}